// Round 1
// baseline (2500.684 us; speedup 1.0000x reference)
//
#include <hip/hip_runtime.h>
#include <math.h>

#define IN_C   256
#define OUT_C  512
#define HW     3136
#define W_     56
#define D_     2304
#define TBL    16
#define MO     16

// ws layout (4-byte units):
// [0,2304)      max_row (float)
// [2304,2816)   hashk (int)
// [2816]        qidx (int)
// [2817]        count_eff (int)
// [2818]        scale_mul (float)
// [2819,3331)   active (int)

// ---------- Kernel A: per-channel 9-rectangle maxes -> max_row ----------
__global__ __launch_bounds__(256) void k_chanmax(const float* __restrict__ x,
                                                 float* __restrict__ ws) {
  int c = blockIdx.x, t = threadIdx.x;
  float m[3][3];
#pragma unroll
  for (int i = 0; i < 3; i++)
#pragma unroll
    for (int j = 0; j < 3; j++) m[i][j] = -INFINITY;

  for (int e = t; e < 16 * HW; e += 256) {
    int n = e / HW;
    int rem = e - n * HW;
    int r = rem / W_;
    int s = rem - r * W_;
    float v = x[(size_t)(n * IN_C + c) * HW + rem];
    bool rc[3] = { r <= 54, true, r >= 1 };
    bool sc[3] = { s <= 54, true, s >= 1 };
#pragma unroll
    for (int i = 0; i < 3; i++)
#pragma unroll
      for (int j = 0; j < 3; j++)
        if (rc[i] && sc[j]) m[i][j] = fmaxf(m[i][j], v);
  }
  // wave reduce (64 lanes)
#pragma unroll
  for (int i = 0; i < 3; i++)
#pragma unroll
    for (int j = 0; j < 3; j++)
      for (int o = 32; o; o >>= 1)
        m[i][j] = fmaxf(m[i][j], __shfl_down(m[i][j], o, 64));

  __shared__ float red[4][9];
  int lane = t & 63, wid = t >> 6;
  if (lane == 0) {
#pragma unroll
    for (int i = 0; i < 3; i++)
#pragma unroll
      for (int j = 0; j < 3; j++) red[wid][i * 3 + j] = m[i][j];
  }
  __syncthreads();
  if (t < 9) {
    float v = fmaxf(fmaxf(red[0][t], red[1][t]), fmaxf(red[2][t], red[3][t]));
    int i = t / 3, j = t - i * 3;
    if (i != 1 || j != 1) v = fmaxf(v, 0.0f);  // padding zeros participate
    ws[(size_t)t * IN_C + c] = v;              // row (i*3+j)*256 + c
  }
}

// ---------- Kernel B: query hash ----------
__global__ __launch_bounds__(256) void k_qhash(const float* __restrict__ a,
                                               float* __restrict__ ws) {
  const float* max_row = ws;
  int t = threadIdx.x;
  double sd = 0.0, sq = 0.0;
  for (int d = t; d < D_; d += 256) {
    double v = (double)max_row[d];
    sd += (double)a[d] * v;
    sq += v * v;
  }
  __shared__ double sh[8], sh2[8];
  int lane = t & 63, wid = t >> 6;
  for (int o = 32; o; o >>= 1) {
    sd += __shfl_down(sd, o, 64);
    sq += __shfl_down(sq, o, 64);
  }
  if (lane == 0) { sh[wid] = sd; sh2[wid] = sq; }
  __syncthreads();
  if (t == 0) {
    double td = 0, tq = 0;
    for (int w = 0; w < 4; w++) { td += sh[w]; tq += sh2[w]; }
    double dot = td / sqrt(tq);
    dot += 0.5 * ((double)a[D_] + (double)a[D_ + 1] + (double)a[D_ + 2] +
                  (double)a[D_ + 3] + (double)a[D_ + 4]);
    long long h = (long long)floor(dot);
    ((int*)ws)[2816] = (int)((h % TBL + TBL) % TBL);
  }
}

// ---------- Kernel C: per-kernel-row hash ----------
__global__ __launch_bounds__(256) void k_khash(const float* __restrict__ kern,
                                               const float* __restrict__ a,
                                               float* __restrict__ ws) {
  int o = blockIdx.x, t = threadIdx.x;
  const float* kr = kern + (size_t)o * D_;
  double sd = 0, sn = 0;
  for (int d = t; d < D_; d += 256) {
    double w = (double)kr[d];
    sd += (double)a[d] * w;
    sn += w * w;
  }
  __shared__ double sh[8], sh2[8];
  int lane = t & 63, wid = t >> 6;
  for (int off = 32; off; off >>= 1) {
    sd += __shfl_down(sd, off, 64);
    sn += __shfl_down(sn, off, 64);
  }
  if (lane == 0) { sh[wid] = sd; sh2[wid] = sn; }
  __syncthreads();
  if (t == 0) {
    double td = 0, tn = 0;
    for (int w = 0; w < 4; w++) { td += sh[w]; tn += sh2[w]; }
    double p1 = tn, p2 = p1 * p1, p4 = p2 * p2, p8 = p4 * p4, p16 = p8 * p8;
    td += (double)a[D_] * p1 + (double)a[D_ + 1] * p2 + (double)a[D_ + 2] * p4 +
          (double)a[D_ + 3] * p8 + (double)a[D_ + 4] * p16;
    long long h = (long long)floor(td);
    ((int*)ws)[2304 + o] = (int)((h % TBL + TBL) % TBL);
  }
}

// ---------- Kernel D: mask + compaction + scale ----------
__global__ __launch_bounds__(512) void k_select(float* __restrict__ ws) {
  int t = threadIdx.x;
  int* hashk = (int*)ws + 2304;
  int* qidx = (int*)ws + 2816;
  int* cntp = (int*)ws + 2817;
  float* scalep = ws + 2818;
  int* active = (int*)ws + 2819;
  __shared__ int cnt;
  if (t == 0) cnt = 0;
  active[t] = 0;  // safe default for padded slots
  __syncthreads();
  int q = *qidx;
  if (hashk[t] == q) {
    int p = atomicAdd(&cnt, 1);
    active[p] = t;
  }
  __syncthreads();
  int c = cnt;
  if (c == 0) active[t] = t;  // fallback: all channels, scale 1
  if (t == 0) {
    if (c > 0) { *cntp = c; *scalep = 512.0f / (float)c; }
    else       { *cntp = 512; *scalep = 1.0f; }
  }
}

// ---------- Kernel F: bias broadcast fill (whole output) ----------
__global__ __launch_bounds__(256) void k_biasfill(const float* __restrict__ bias,
                                                  float* __restrict__ out) {
  const int total4 = 16 * OUT_C * HW / 4;  // 6422528
  int stride = gridDim.x * blockDim.x;
  for (int i = blockIdx.x * blockDim.x + threadIdx.x; i < total4; i += stride) {
    int o = (i / 784) & (OUT_C - 1);
    float b = bias[o];
    ((float4*)out)[i] = make_float4(b, b, b, b);
  }
}

// ---------- Kernel E: direct conv for active channels ----------
__global__ __launch_bounds__(256) void k_conv(const float* __restrict__ x,
                                              const float* __restrict__ kern,
                                              const float* __restrict__ bias,
                                              const float* __restrict__ ws,
                                              float* __restrict__ out) {
  const int* cntp = (const int*)ws + 2817;
  int cnt = *cntp;
  int g = blockIdx.y;
  if (g * MO >= cnt) return;
  const int* active = (const int*)ws + 2819;
  float sc = ws[2818];
  int n = blockIdx.z;
  int ybase = blockIdx.x * 4;
  int t = threadIdx.x;
  int oc_sub = t & 3;         // 4 oc-groups of 4
  int px_sub = t >> 2;        // 0..63
  int ly = px_sub >> 4;       // 0..3 rows
  int col4 = (px_sub & 15) << 2;  // 0..60 (56,60 dummy, not stored)

  __shared__ float itile[16][6][68];   // c_local, row(-1..+4), col(-1..)
  __shared__ float wtile[9][16][16];   // tap, c_local, oc_lo

  float acc[4][4];
#pragma unroll
  for (int u = 0; u < 4; u++)
#pragma unroll
    for (int v = 0; v < 4; v++) acc[u][v] = 0.f;

  for (int cc = 0; cc < 16; ++cc) {
    int cbase = cc * 16;
    // weights for this c-chunk: 9 taps x 16 c x 16 oc
    for (int e = t; e < 2304; e += 256) {
      int oc_lo = e / 144;
      int r = e - oc_lo * 144;
      int tap = r >> 4;
      int cl = r & 15;
      int oc = active[g * MO + oc_lo];
      wtile[tap][cl][oc_lo] = kern[(size_t)oc * D_ + tap * IN_C + cbase + cl];
    }
    // input tile with halo: 16 c x 6 rows x 58 cols (stored in 68-wide rows)
    for (int e = t; e < 16 * 6 * 68; e += 256) {
      int cl = e / 408;
      int r = e - cl * 408;
      int ri = r / 68;
      int ci = r - ri * 68;
      int y = ybase + ri - 1;
      int xx = ci - 1;
      float v = 0.f;
      if ((unsigned)y < 56u && (unsigned)xx < 56u)
        v = x[(size_t)(n * IN_C + cbase + cl) * HW + y * W_ + xx];
      itile[cl][ri][ci] = v;
    }
    __syncthreads();
#pragma unroll 4
    for (int cl = 0; cl < 16; ++cl) {
#pragma unroll
      for (int i = 0; i < 3; i++) {
        const float* prow = &itile[cl][ly + i][col4];
        float4 p0 = *(const float4*)prow;
        float2 p1 = *(const float2*)(prow + 4);
        float pv[6] = {p0.x, p0.y, p0.z, p0.w, p1.x, p1.y};
#pragma unroll
        for (int j = 0; j < 3; j++) {
          float4 wv = *(const float4*)&wtile[i * 3 + j][cl][oc_sub << 2];
          float wa[4] = {wv.x, wv.y, wv.z, wv.w};
#pragma unroll
          for (int oo = 0; oo < 4; oo++)
#pragma unroll
            for (int p = 0; p < 4; p++)
              acc[oo][p] = fmaf(wa[oo], pv[j + p], acc[oo][p]);
        }
      }
    }
    __syncthreads();
  }

  if (col4 < 56) {
    int y = ybase + ly;
#pragma unroll
    for (int oo = 0; oo < 4; oo++) {
      int slot = g * MO + (oc_sub << 2) + oo;
      if (slot < cnt) {
        int oc = active[slot];
        float b = bias[oc];
        float4 v = make_float4(acc[oo][0] * sc + b, acc[oo][1] * sc + b,
                               acc[oo][2] * sc + b, acc[oo][3] * sc + b);
        *(float4*)&out[((size_t)n * OUT_C + oc) * HW + y * W_ + col4] = v;
      }
    }
  }
}

extern "C" void kernel_launch(void* const* d_in, const int* in_sizes, int n_in,
                              void* d_out, int out_size, void* d_ws, size_t ws_size,
                              hipStream_t stream) {
  const float* x    = (const float*)d_in[0];
  const float* kern = (const float*)d_in[1];
  const float* bias = (const float*)d_in[2];
  const float* a    = (const float*)d_in[3];
  float* out = (float*)d_out;
  float* ws  = (float*)d_ws;

  k_chanmax<<<dim3(IN_C), dim3(256), 0, stream>>>(x, ws);
  k_qhash<<<dim3(1), dim3(256), 0, stream>>>(a, ws);
  k_khash<<<dim3(OUT_C), dim3(256), 0, stream>>>(kern, a, ws);
  k_select<<<dim3(1), dim3(512), 0, stream>>>(ws);
  k_biasfill<<<dim3(4096), dim3(256), 0, stream>>>(bias, out);
  k_conv<<<dim3(14, OUT_C / MO, 16), dim3(256), 0, stream>>>(x, kern, bias, ws, out);
}

// Round 2
// 556.847 us; speedup vs baseline: 4.4908x; 4.4908x over previous
//
#include <hip/hip_runtime.h>
#include <math.h>

#define IN_C   256
#define OUT_C  512
#define HW     3136
#define W_     56
#define D_     2304
#define TBL    16

// ws layout (4-byte units):
// [0,2304)      max_row (float)
// [2304,2816)   hashk (int)
// [2816]        qidx (int)
// [2817]        count_eff (int)
// [2818]        scale_mul (float)
// [2819,3331)   active (int)
// [3331,3843)   flags (int, 1 = channel is computed by conv)
// byte 16384+   Wc: bf16 weights, compacted active rows [512][2304]

typedef __attribute__((ext_vector_type(8))) __bf16 bf16x8;
typedef __attribute__((ext_vector_type(4))) float f32x4;

__device__ __forceinline__ ushort f2bf(float f) {
  uint b = __float_as_uint(f);
  b = b + 0x7FFFu + ((b >> 16) & 1u);
  return (ushort)(b >> 16);
}

// ---------- Kernel A: per-channel 9-rectangle maxes -> max_row ----------
__global__ __launch_bounds__(256) void k_chanmax(const float* __restrict__ x,
                                                 float* __restrict__ ws) {
  int c = blockIdx.x, t = threadIdx.x;
  float m[3][3];
#pragma unroll
  for (int i = 0; i < 3; i++)
#pragma unroll
    for (int j = 0; j < 3; j++) m[i][j] = -INFINITY;

  for (int e = t; e < 16 * HW; e += 256) {
    int n = e / HW;
    int rem = e - n * HW;
    int r = rem / W_;
    int s = rem - r * W_;
    float v = x[(size_t)(n * IN_C + c) * HW + rem];
    bool rc[3] = { r <= 54, true, r >= 1 };
    bool sc[3] = { s <= 54, true, s >= 1 };
#pragma unroll
    for (int i = 0; i < 3; i++)
#pragma unroll
      for (int j = 0; j < 3; j++)
        if (rc[i] && sc[j]) m[i][j] = fmaxf(m[i][j], v);
  }
#pragma unroll
  for (int i = 0; i < 3; i++)
#pragma unroll
    for (int j = 0; j < 3; j++)
      for (int o = 32; o; o >>= 1)
        m[i][j] = fmaxf(m[i][j], __shfl_down(m[i][j], o, 64));

  __shared__ float red[4][9];
  int lane = t & 63, wid = t >> 6;
  if (lane == 0) {
#pragma unroll
    for (int i = 0; i < 3; i++)
#pragma unroll
      for (int j = 0; j < 3; j++) red[wid][i * 3 + j] = m[i][j];
  }
  __syncthreads();
  if (t < 9) {
    float v = fmaxf(fmaxf(red[0][t], red[1][t]), fmaxf(red[2][t], red[3][t]));
    int i = t / 3, j = t - i * 3;
    if (i != 1 || j != 1) v = fmaxf(v, 0.0f);  // padding zeros participate
    ws[(size_t)t * IN_C + c] = v;
  }
}

// ---------- Kernel B: query hash ----------
__global__ __launch_bounds__(256) void k_qhash(const float* __restrict__ a,
                                               float* __restrict__ ws) {
  const float* max_row = ws;
  int t = threadIdx.x;
  double sd = 0.0, sq = 0.0;
  for (int d = t; d < D_; d += 256) {
    double v = (double)max_row[d];
    sd += (double)a[d] * v;
    sq += v * v;
  }
  __shared__ double sh[8], sh2[8];
  int lane = t & 63, wid = t >> 6;
  for (int o = 32; o; o >>= 1) {
    sd += __shfl_down(sd, o, 64);
    sq += __shfl_down(sq, o, 64);
  }
  if (lane == 0) { sh[wid] = sd; sh2[wid] = sq; }
  __syncthreads();
  if (t == 0) {
    double td = 0, tq = 0;
    for (int w = 0; w < 4; w++) { td += sh[w]; tq += sh2[w]; }
    double dot = td / sqrt(tq);
    dot += 0.5 * ((double)a[D_] + (double)a[D_ + 1] + (double)a[D_ + 2] +
                  (double)a[D_ + 3] + (double)a[D_ + 4]);
    long long h = (long long)floor(dot);
    ((int*)ws)[2816] = (int)((h % TBL + TBL) % TBL);
  }
}

// ---------- Kernel C: per-kernel-row hash ----------
__global__ __launch_bounds__(256) void k_khash(const float* __restrict__ kern,
                                               const float* __restrict__ a,
                                               float* __restrict__ ws) {
  int o = blockIdx.x, t = threadIdx.x;
  const float* kr = kern + (size_t)o * D_;
  double sd = 0, sn = 0;
  for (int d = t; d < D_; d += 256) {
    double w = (double)kr[d];
    sd += (double)a[d] * w;
    sn += w * w;
  }
  __shared__ double sh[8], sh2[8];
  int lane = t & 63, wid = t >> 6;
  for (int off = 32; off; off >>= 1) {
    sd += __shfl_down(sd, off, 64);
    sn += __shfl_down(sn, off, 64);
  }
  if (lane == 0) { sh[wid] = sd; sh2[wid] = sn; }
  __syncthreads();
  if (t == 0) {
    double td = 0, tn = 0;
    for (int w = 0; w < 4; w++) { td += sh[w]; tn += sh2[w]; }
    double p1 = tn, p2 = p1 * p1, p4 = p2 * p2, p8 = p4 * p4, p16 = p8 * p8;
    td += (double)a[D_] * p1 + (double)a[D_ + 1] * p2 + (double)a[D_ + 2] * p4 +
          (double)a[D_ + 3] * p8 + (double)a[D_ + 4] * p16;
    long long h = (long long)floor(td);
    ((int*)ws)[2304 + o] = (int)((h % TBL + TBL) % TBL);
  }
}

// ---------- Kernel D: mask + compaction + scale + flags ----------
__global__ __launch_bounds__(512) void k_select(float* __restrict__ ws) {
  int t = threadIdx.x;
  int* hashk = (int*)ws + 2304;
  int* qidx = (int*)ws + 2816;
  int* cntp = (int*)ws + 2817;
  float* scalep = ws + 2818;
  int* active = (int*)ws + 2819;
  int* flags = (int*)ws + 3331;
  __shared__ int cnt;
  if (t == 0) cnt = 0;
  active[t] = 0;
  __syncthreads();
  int q = *qidx;
  bool m = (hashk[t] == q);
  if (m) {
    int p = atomicAdd(&cnt, 1);
    active[p] = t;
  }
  __syncthreads();
  int c = cnt;
  flags[t] = (c == 0) ? 1 : (m ? 1 : 0);
  if (c == 0) active[t] = t;  // fallback: all channels, scale 1
  if (t == 0) {
    if (c > 0) { *cntp = c; *scalep = 512.0f / (float)c; }
    else       { *cntp = 512; *scalep = 1.0f; }
  }
}

// ---------- Kernel P: compact + bf16-convert active weight rows ----------
__global__ __launch_bounds__(256) void k_prep(const float* __restrict__ kern,
                                              float* __restrict__ ws) {
  const int* iws = (const int*)ws;
  int cnt = iws[2817];
  const int* active = iws + 2819;
  ushort* Wc = (ushort*)((char*)ws + 16384);
  int s = blockIdx.x, t = threadIdx.x;
  if (s < cnt) {
    int oc = active[s];
    const float* src = kern + (size_t)oc * D_;
    for (int e = t; e < D_; e += 256) Wc[(size_t)s * D_ + e] = f2bf(src[e]);
  } else {
    for (int e = t; e < D_; e += 256) Wc[(size_t)s * D_ + e] = 0;
  }
}

// ---------- Kernel F: bias fill for inactive channels only ----------
__global__ __launch_bounds__(256) void k_biasfill(const float* __restrict__ bias,
                                                  const float* __restrict__ ws,
                                                  float* __restrict__ out) {
  const int* flags = (const int*)ws + 3331;
  const int total4 = 16 * OUT_C * HW / 4;  // 6422528
  int stride = gridDim.x * blockDim.x;
  for (int i = blockIdx.x * blockDim.x + threadIdx.x; i < total4; i += stride) {
    int o = (i / 784) & (OUT_C - 1);
    if (!flags[o]) {
      float b = bias[o];
      ((float4*)out)[i] = make_float4(b, b, b, b);
    }
  }
}

// ---------- Kernel E: implicit-GEMM MFMA conv, 128oc x 128px tile ----------
__global__ __launch_bounds__(256) void k_conv(const float* __restrict__ x,
                                              const float* __restrict__ bias,
                                              const float* __restrict__ ws,
                                              float* __restrict__ out) {
  const int* iws = (const int*)ws;
  int cnt = iws[2817];
  int octile = blockIdx.y;
  if (octile * 128 >= cnt) return;
  float sc = ws[2818];
  const int* active = iws + 2819;
  const ushort* Wc = (const ushort*)((const char*)ws + 16384);

  int tile = blockIdx.x;
  int t = threadIdx.x;
  int lane = t & 63, wid = t >> 6;
  int quad = lane >> 4, l16 = lane & 15;
  int ochalf = wid & 1, pxhalf = wid >> 1;

  __shared__ __align__(16) ushort A_lds[128 * 32];
  __shared__ __align__(16) ushort B_lds[128 * 32];

  // B staging coords (thread-fixed): thread covers px=t&127, 16 c's (chalf)
  int px = t & 127;
  int chalf = t >> 7;
  int pxg = tile * 128 + px;
  int n_img = pxg / HW;
  int rem = pxg - n_img * HW;
  int y = rem / W_;
  int xcol = rem - y * W_;
  const float* xin = x + (size_t)n_img * IN_C * HW;

  f32x4 acc[4][4];
#pragma unroll
  for (int a = 0; a < 4; a++)
#pragma unroll
    for (int b = 0; b < 4; b++) acc[a][b] = (f32x4){0.f, 0.f, 0.f, 0.f};

  for (int chunk = 0; chunk < 72; ++chunk) {
    int tap = chunk >> 3, c0 = (chunk & 7) << 5;
    int ti = tap / 3;
    int di = ti - 1, dj = (tap - ti * 3) - 1;

    __syncthreads();  // previous iteration's frag reads done before overwrite

    // ---- stage A: 8 KB, 512 x 16B, XOR-swizzled on the global side ----
#pragma unroll
    for (int e0 = 0; e0 < 2; e0++) {
      int e = t + e0 * 256;
      int row = e >> 2, seg = e & 3;
      int gseg = seg ^ (row & 3);
      uint4 v = *(const uint4*)(Wc + (size_t)(octile * 128 + row) * D_ +
                                tap * IN_C + c0 + gseg * 8);
      *(uint4*)(A_lds + e * 8) = v;
    }

    // ---- stage B: gather fp32, cvt bf16, swizzled ds_write_b64 ----
    {
      int yy = y + di, xx = xcol + dj;
      bool valid = ((unsigned)yy < 56u) && ((unsigned)xx < 56u);
      const float* src = xin + (size_t)(c0 + chalf * 16) * HW + yy * W_ + xx;
      float vv[16];
#pragma unroll
      for (int e = 0; e < 16; e++) vv[e] = 0.f;
      if (valid) {
#pragma unroll
        for (int e = 0; e < 16; e++) vv[e] = src[(size_t)e * HW];
      }
#pragma unroll
      for (int w4 = 0; w4 < 4; ++w4) {
        uint p0 = (uint)f2bf(vv[w4 * 4 + 0]) | ((uint)f2bf(vv[w4 * 4 + 1]) << 16);
        uint p1 = (uint)f2bf(vv[w4 * 4 + 2]) | ((uint)f2bf(vv[w4 * 4 + 3]) << 16);
        int k = chalf * 16 + w4 * 4;
        int block = ((k >> 3) ^ px) & 3;
        uint2 pr; pr.x = p0; pr.y = p1;
        *(uint2*)((char*)B_lds + px * 64 + block * 16 + (k & 7) * 2) = pr;
      }
    }
    __syncthreads();

    // ---- fragments + MFMA ----
    bf16x8 af[4], bfr[4];
#pragma unroll
    for (int a = 0; a < 4; a++) {
      int row = ochalf * 64 + a * 16 + l16;
      int block = (quad ^ row) & 3;
      union { uint4 u; bf16x8 v; } c;
      c.u = *(const uint4*)(A_lds + row * 32 + block * 8);
      af[a] = c.v;
    }
#pragma unroll
    for (int b = 0; b < 4; b++) {
      int row = pxhalf * 64 + b * 16 + l16;
      int block = (quad ^ row) & 3;
      union { uint4 u; bf16x8 v; } c;
      c.u = *(const uint4*)(B_lds + row * 32 + block * 8);
      bfr[b] = c.v;
    }
#pragma unroll
    for (int a = 0; a < 4; a++)
#pragma unroll
      for (int b = 0; b < 4; b++)
        acc[a][b] = __builtin_amdgcn_mfma_f32_16x16x32_bf16(af[a], bfr[b],
                                                            acc[a][b], 0, 0, 0);
  }

  // ---- epilogue: C[m=quad*4+r][n=l16], scale + bias, scatter to NCHW ----
  int ocv[4][4];
  float bv[4][4];
#pragma unroll
  for (int a = 0; a < 4; a++)
#pragma unroll
    for (int r = 0; r < 4; r++) {
      int slot = octile * 128 + ochalf * 64 + a * 16 + quad * 4 + r;
      if (slot < cnt) {
        int oc = active[slot];
        ocv[a][r] = oc;
        bv[a][r] = bias[oc];
      } else {
        ocv[a][r] = -1;
        bv[a][r] = 0.f;
      }
    }
#pragma unroll
  for (int b = 0; b < 4; b++) {
    int pxl = pxhalf * 64 + b * 16 + l16;
    int pg = tile * 128 + pxl;
    int ni = pg / HW;
    int rm = pg - ni * HW;
    size_t obase = (size_t)ni * OUT_C * HW + rm;
#pragma unroll
    for (int a = 0; a < 4; a++)
#pragma unroll
      for (int r = 0; r < 4; r++) {
        if (ocv[a][r] >= 0)
          out[obase + (size_t)ocv[a][r] * HW] = acc[a][b][r] * sc + bv[a][r];
      }
  }
}

extern "C" void kernel_launch(void* const* d_in, const int* in_sizes, int n_in,
                              void* d_out, int out_size, void* d_ws, size_t ws_size,
                              hipStream_t stream) {
  const float* x    = (const float*)d_in[0];
  const float* kern = (const float*)d_in[1];
  const float* bias = (const float*)d_in[2];
  const float* a    = (const float*)d_in[3];
  float* out = (float*)d_out;
  float* ws  = (float*)d_ws;

  k_chanmax<<<dim3(IN_C), dim3(256), 0, stream>>>(x, ws);
  k_qhash<<<dim3(1), dim3(256), 0, stream>>>(a, ws);
  k_khash<<<dim3(OUT_C), dim3(256), 0, stream>>>(kern, a, ws);
  k_select<<<dim3(1), dim3(512), 0, stream>>>(ws);
  k_prep<<<dim3(OUT_C), dim3(256), 0, stream>>>(kern, ws);
  k_biasfill<<<dim3(4096), dim3(256), 0, stream>>>(bias, ws, out);
  k_conv<<<dim3(392, 4), dim3(256), 0, stream>>>(x, bias, ws, out);
}

// Round 5
// 440.730 us; speedup vs baseline: 5.6740x; 1.2635x over previous
//
#include <hip/hip_runtime.h>
#include <math.h>

#define IN_C   256
#define OUT_C  512
#define HW     3136
#define W_     56
#define D_     2304
#define TBL    16

// ws layout (4-byte units) — identical to the round-2 kernel that passed:
// [0,2304)      max_row (float)
// [2304,2816)   hashk (int)
// [2816]        qidx (int)
// [2817]        count_eff (int)
// [2818]        scale_mul (float)
// [2819,3331)   active (int)
// [3331,3843)   flags (int, 1 = channel is computed by conv)
// byte 16384+   Wc: bf16 weights, compacted active rows [512][2304]

typedef __attribute__((ext_vector_type(8))) __bf16 bf16x8;
typedef __attribute__((ext_vector_type(4))) float f32x4;

__device__ __forceinline__ ushort f2bf(float f) {
  uint b = __float_as_uint(f);
  b = b + 0x7FFFu + ((b >> 16) & 1u);
  return (ushort)(b >> 16);
}

// ---------- Kernel A: per-channel 9-rectangle maxes -> max_row ----------
__global__ __launch_bounds__(256) void k_chanmax(const float* __restrict__ x,
                                                 float* __restrict__ ws) {
  int c = blockIdx.x, t = threadIdx.x;
  float m[3][3];
#pragma unroll
  for (int i = 0; i < 3; i++)
#pragma unroll
    for (int j = 0; j < 3; j++) m[i][j] = -INFINITY;

  for (int e = t; e < 16 * HW; e += 256) {
    int n = e / HW;
    int rem = e - n * HW;
    int r = rem / W_;
    int s = rem - r * W_;
    float v = x[(size_t)(n * IN_C + c) * HW + rem];
    bool rc[3] = { r <= 54, true, r >= 1 };
    bool sc[3] = { s <= 54, true, s >= 1 };
#pragma unroll
    for (int i = 0; i < 3; i++)
#pragma unroll
      for (int j = 0; j < 3; j++)
        if (rc[i] && sc[j]) m[i][j] = fmaxf(m[i][j], v);
  }
#pragma unroll
  for (int i = 0; i < 3; i++)
#pragma unroll
    for (int j = 0; j < 3; j++)
      for (int o = 32; o; o >>= 1)
        m[i][j] = fmaxf(m[i][j], __shfl_down(m[i][j], o, 64));

  __shared__ float red[4][9];
  int lane = t & 63, wid = t >> 6;
  if (lane == 0) {
#pragma unroll
    for (int i = 0; i < 3; i++)
#pragma unroll
      for (int j = 0; j < 3; j++) red[wid][i * 3 + j] = m[i][j];
  }
  __syncthreads();
  if (t < 9) {
    float v = fmaxf(fmaxf(red[0][t], red[1][t]), fmaxf(red[2][t], red[3][t]));
    int i = t / 3, j = t - i * 3;
    if (i != 1 || j != 1) v = fmaxf(v, 0.0f);  // padding zeros participate
    ws[(size_t)t * IN_C + c] = v;
  }
}

// ---------- Kernel B: query hash ----------
__global__ __launch_bounds__(256) void k_qhash(const float* __restrict__ a,
                                               float* __restrict__ ws) {
  const float* max_row = ws;
  int t = threadIdx.x;
  double sd = 0.0, sq = 0.0;
  for (int d = t; d < D_; d += 256) {
    double v = (double)max_row[d];
    sd += (double)a[d] * v;
    sq += v * v;
  }
  __shared__ double sh[8], sh2[8];
  int lane = t & 63, wid = t >> 6;
  for (int o = 32; o; o >>= 1) {
    sd += __shfl_down(sd, o, 64);
    sq += __shfl_down(sq, o, 64);
  }
  if (lane == 0) { sh[wid] = sd; sh2[wid] = sq; }
  __syncthreads();
  if (t == 0) {
    double td = 0, tq = 0;
    for (int w = 0; w < 4; w++) { td += sh[w]; tq += sh2[w]; }
    double dot = td / sqrt(tq);
    dot += 0.5 * ((double)a[D_] + (double)a[D_ + 1] + (double)a[D_ + 2] +
                  (double)a[D_ + 3] + (double)a[D_ + 4]);
    long long h = (long long)floor(dot);
    ((int*)ws)[2816] = (int)((h % TBL + TBL) % TBL);
  }
}

// ---------- Kernel C: per-kernel-row hash ----------
__global__ __launch_bounds__(256) void k_khash(const float* __restrict__ kern,
                                               const float* __restrict__ a,
                                               float* __restrict__ ws) {
  int o = blockIdx.x, t = threadIdx.x;
  const float* kr = kern + (size_t)o * D_;
  double sd = 0, sn = 0;
  for (int d = t; d < D_; d += 256) {
    double w = (double)kr[d];
    sd += (double)a[d] * w;
    sn += w * w;
  }
  __shared__ double sh[8], sh2[8];
  int lane = t & 63, wid = t >> 6;
  for (int off = 32; off; off >>= 1) {
    sd += __shfl_down(sd, off, 64);
    sn += __shfl_down(sn, off, 64);
  }
  if (lane == 0) { sh[wid] = sd; sh2[wid] = sn; }
  __syncthreads();
  if (t == 0) {
    double td = 0, tn = 0;
    for (int w = 0; w < 4; w++) { td += sh[w]; tn += sh2[w]; }
    double p1 = tn, p2 = p1 * p1, p4 = p2 * p2, p8 = p4 * p4, p16 = p8 * p8;
    td += (double)a[D_] * p1 + (double)a[D_ + 1] * p2 + (double)a[D_ + 2] * p4 +
          (double)a[D_ + 3] * p8 + (double)a[D_ + 4] * p16;
    long long h = (long long)floor(td);
    ((int*)ws)[2304 + o] = (int)((h % TBL + TBL) % TBL);
  }
}

// ---------- Kernel D: mask + compaction + scale + flags ----------
__global__ __launch_bounds__(512) void k_select(float* __restrict__ ws) {
  int t = threadIdx.x;
  int* hashk = (int*)ws + 2304;
  int* qidx = (int*)ws + 2816;
  int* cntp = (int*)ws + 2817;
  float* scalep = ws + 2818;
  int* active = (int*)ws + 2819;
  int* flags = (int*)ws + 3331;
  __shared__ int cnt;
  if (t == 0) cnt = 0;
  active[t] = 0;
  __syncthreads();
  int q = *qidx;
  bool m = (hashk[t] == q);
  if (m) {
    int p = atomicAdd(&cnt, 1);
    active[p] = t;
  }
  __syncthreads();
  int c = cnt;
  flags[t] = (c == 0) ? 1 : (m ? 1 : 0);
  if (c == 0) active[t] = t;  // fallback: all channels, scale 1
  if (t == 0) {
    if (c > 0) { *cntp = c; *scalep = 512.0f / (float)c; }
    else       { *cntp = 512; *scalep = 1.0f; }
  }
}

// ---------- Kernel P: compact + bf16-convert active weight rows ----------
__global__ __launch_bounds__(256) void k_prep(const float* __restrict__ kern,
                                              float* __restrict__ ws) {
  const int* iws = (const int*)ws;
  int cnt = iws[2817];
  const int* active = iws + 2819;
  ushort* Wc = (ushort*)((char*)ws + 16384);
  int s = blockIdx.x, t = threadIdx.x;
  if (s < cnt) {
    int oc = active[s];
    const float* src = kern + (size_t)oc * D_;
    for (int e = t; e < D_; e += 256) Wc[(size_t)s * D_ + e] = f2bf(src[e]);
  } else {
    for (int e = t; e < D_; e += 256) Wc[(size_t)s * D_ + e] = 0;
  }
}

// ---------- Kernel F: bias fill for inactive channels only ----------
__global__ __launch_bounds__(256) void k_biasfill(const float* __restrict__ bias,
                                                  const float* __restrict__ ws,
                                                  float* __restrict__ out) {
  const int* flags = (const int*)ws + 3331;
  const int total4 = 16 * OUT_C * HW / 4;  // 6422528
  int stride = gridDim.x * blockDim.x;
  for (int i = blockIdx.x * blockDim.x + threadIdx.x; i < total4; i += stride) {
    int o = (i / 784) & (OUT_C - 1);
    if (!flags[o]) {
      float b = bias[o];
      ((float4*)out)[i] = make_float4(b, b, b, b);
    }
  }
}

// ---------- Kernel E: implicit-GEMM MFMA conv ----------
// Block: 128 oc x 224 px (4 image rows). x staged once per c-chunk into a
// 6-row x 58-col halo tile, reused by all 9 taps. A staged 3 taps at a time.
// Rows padded to 80 B: frag reads/writes hit the 8-cyc LDS floor (2-way max).
#define XSTRIDE 40   // ushorts per X row (32 used + 8 pad)
#define ASTRIDE 104  // ushorts per A row (96 used + 8 pad)
__global__ __launch_bounds__(256, 2) void k_conv(const float* __restrict__ x,
                                                 const float* __restrict__ bias,
                                                 const float* __restrict__ ws,
                                                 float* __restrict__ out) {
  const int* iws = (const int*)ws;
  int cnt = iws[2817];
  int octile = blockIdx.y;
  if (octile * 128 >= cnt) return;
  float sc = ws[2818];
  const int* active = iws + 2819;
  const ushort* Wc = (const ushort*)((const char*)ws + 16384);

  int rt = blockIdx.x;          // row tile: image rows 4rt..4rt+3
  int n = blockIdx.z;
  int t = threadIdx.x;
  int lane = t & 63, wid = t >> 6;
  int quad = lane >> 4, l16 = lane & 15;
  int ochalf = wid & 1, pxhalf = wid >> 1;

  __shared__ __align__(16) ushort X_lds[348 * XSTRIDE];  // 27840 B
  __shared__ __align__(16) ushort A_lds[128 * ASTRIDE];  // 26624 B

  const float* xin = x + (size_t)n * IN_C * HW;

  // per-b px coords and X base addresses (center tap)
  int pbase[7];
#pragma unroll
  for (int b = 0; b < 7; b++) {
    int pxl = pxhalf * 112 + b * 16 + l16;
    int rl = pxl / 56;
    int col = pxl - rl * 56;
    pbase[b] = ((rl + 1) * 58 + (col + 1)) * XSTRIDE;
  }

  f32x4 acc[4][7];
#pragma unroll
  for (int a = 0; a < 4; a++)
#pragma unroll
    for (int b = 0; b < 7; b++) acc[a][b] = (f32x4){0.f, 0.f, 0.f, 0.f};

  for (int cc = 0; cc < 8; ++cc) {
    int c0 = cc * 32;
    __syncthreads();  // X reuse guard
    // ---- stage X: 6 rows x 58 cols x 32 c, fp32->bf16 ----
    for (int e = t; e < 1392; e += 256) {
      int q = e / 348;
      int p = e - q * 348;
      int rl = p / 58;
      int cp = p - rl * 58;
      int y = rt * 4 - 1 + rl;
      int xx = cp - 1;
      float vv[8];
      if ((unsigned)y < 56u && (unsigned)xx < 56u) {
        const float* src = xin + (size_t)(c0 + q * 8) * HW + y * W_ + xx;
#pragma unroll
        for (int k = 0; k < 8; k++) vv[k] = src[(size_t)k * HW];
      } else {
#pragma unroll
        for (int k = 0; k < 8; k++) vv[k] = 0.f;
      }
      uint4 pk;
      pk.x = (uint)f2bf(vv[0]) | ((uint)f2bf(vv[1]) << 16);
      pk.y = (uint)f2bf(vv[2]) | ((uint)f2bf(vv[3]) << 16);
      pk.z = (uint)f2bf(vv[4]) | ((uint)f2bf(vv[5]) << 16);
      pk.w = (uint)f2bf(vv[6]) | ((uint)f2bf(vv[7]) << 16);
      *(uint4*)&X_lds[p * XSTRIDE + q * 8] = pk;
    }

    for (int kh = 0; kh < 3; ++kh) {
      __syncthreads();  // prev A reads done (also orders X for kh=0)
      // ---- stage A: 128 oc x 3 taps x 32 c ----
      for (int e = t; e < 1536; e += 256) {
        int oc = e / 12;
        int seg = e - oc * 12;
        int tl = seg >> 2, q = seg & 3;
        uint4 v = *(const uint4*)(Wc + (size_t)(octile * 128 + oc) * D_ +
                                  (kh * 3 + tl) * IN_C + c0 + q * 8);
        *(uint4*)&A_lds[oc * ASTRIDE + tl * 32 + q * 8] = v;
      }
      __syncthreads();

      int di = kh - 1;
#pragma unroll
      for (int djj = 0; djj < 3; ++djj) {
        int poff = (di * 58 + (djj - 1)) * XSTRIDE + quad * 8;
        bf16x8 bfr[7];
#pragma unroll
        for (int b = 0; b < 7; b++) {
          union { uint4 u; bf16x8 v; } cv;
          cv.u = *(const uint4*)&X_lds[pbase[b] + poff];
          bfr[b] = cv.v;
        }
#pragma unroll
        for (int a = 0; a < 4; a++) {
          union { uint4 u; bf16x8 v; } cv;
          cv.u = *(const uint4*)&A_lds[(ochalf * 64 + a * 16 + l16) * ASTRIDE +
                                       djj * 32 + quad * 8];
          bf16x8 af = cv.v;
#pragma unroll
          for (int b = 0; b < 7; b++)
            acc[a][b] = __builtin_amdgcn_mfma_f32_16x16x32_bf16(af, bfr[b],
                                                                acc[a][b], 0, 0, 0);
        }
      }
    }
  }

  // ---- epilogue: C[m=quad*4+r (oc), n=l16 (px)] ----
  size_t nbase = (size_t)n * OUT_C * HW;
#pragma unroll
  for (int a = 0; a < 4; a++) {
#pragma unroll
    for (int r = 0; r < 4; r++) {
      int slot = octile * 128 + ochalf * 64 + a * 16 + quad * 4 + r;
      if (slot < cnt) {
        int oc = active[slot];
        float bv = bias[oc];
        size_t obase = nbase + (size_t)oc * HW + rt * 224 + pxhalf * 112 + l16;
#pragma unroll
        for (int b = 0; b < 7; b++)
          out[obase + b * 16] = acc[a][b][r] * sc + bv;
      }
    }
  }
}

extern "C" void kernel_launch(void* const* d_in, const int* in_sizes, int n_in,
                              void* d_out, int out_size, void* d_ws, size_t ws_size,
                              hipStream_t stream) {
  const float* x    = (const float*)d_in[0];
  const float* kern = (const float*)d_in[1];
  const float* bias = (const float*)d_in[2];
  const float* a    = (const float*)d_in[3];
  float* out = (float*)d_out;
  float* ws  = (float*)d_ws;

  k_chanmax<<<dim3(IN_C), dim3(256), 0, stream>>>(x, ws);
  k_qhash<<<dim3(1), dim3(256), 0, stream>>>(a, ws);
  k_khash<<<dim3(OUT_C), dim3(256), 0, stream>>>(kern, a, ws);
  k_select<<<dim3(1), dim3(512), 0, stream>>>(ws);
  k_prep<<<dim3(OUT_C), dim3(256), 0, stream>>>(kern, ws);
  k_biasfill<<<dim3(4096), dim3(256), 0, stream>>>(bias, ws, out);
  k_conv<<<dim3(14, 4, 16), dim3(256), 0, stream>>>(x, bias, ws, out);
}